// Round 7
// baseline (289.217 us; speedup 1.0000x reference)
//
#include <hip/hip_runtime.h>
#include <math.h>

#define B_     2
#define S_     1500
#define HID_   1024
#define NH_    16
#define HD_    64
#define M_     (B_*S_)   // 3000
#define SP_    1536      // padded S for transposed-V rows
#define LOG2E  1.4426950408889634f

typedef short bf16x8 __attribute__((ext_vector_type(8)));
typedef short bf16x4 __attribute__((ext_vector_type(4)));
typedef float f32x4  __attribute__((ext_vector_type(4)));

__device__ __forceinline__ float b2f(short s) {
    unsigned u = ((unsigned)(unsigned short)s) << 16;
    return __uint_as_float(u);
}
__device__ __forceinline__ short f2b(float f) {   // RNE, finite inputs
    unsigned u = __float_as_uint(f);
    unsigned r = (u + 0x7FFFu + ((u >> 16) & 1u)) >> 16;
    return (short)r;
}
__device__ __forceinline__ void gload16(const short* src, short* lds) {
    __builtin_amdgcn_global_load_lds(
        (const __attribute__((address_space(1))) void*)src,
        (__attribute__((address_space(3))) void*)lds, 16, 0, 0);
}

// ---------------------------------------------------------------------------
// f32 -> bf16 for the three activations, one launch
__global__ __launch_bounds__(256) void cvt_act3(
    const float* __restrict__ q, const float* __restrict__ k,
    const float* __restrict__ v, short* __restrict__ oq,
    short* __restrict__ ok, short* __restrict__ ov)
{
    const float* src = blockIdx.y == 0 ? q : blockIdx.y == 1 ? k : v;
    short* dst       = blockIdx.y == 0 ? oq : blockIdx.y == 1 ? ok : ov;
    int i = blockIdx.x * 256 + threadIdx.x;      // < 384000
    const float4* p = (const float4*)(src + (size_t)i * 8);
    float4 a = p[0], b = p[1];
    bf16x8 o;
    o[0]=f2b(a.x); o[1]=f2b(a.y); o[2]=f2b(a.z); o[3]=f2b(a.w);
    o[4]=f2b(b.x); o[5]=f2b(b.y); o[6]=f2b(b.z); o[7]=f2b(b.w);
    *(bf16x8*)(dst + (size_t)i * 8) = o;
}

// ---------------------------------------------------------------------------
// all weight prep in one launch; Wq/bq fold 0.125*log2e
__global__ __launch_bounds__(256) void prep_w(
    const float* __restrict__ Wq, const float* __restrict__ Wk,
    const float* __restrict__ Wv, const float* __restrict__ Wfc,
    const float* __restrict__ pe_k, const float* __restrict__ pe_v,
    short* __restrict__ Wqt, short* __restrict__ Wkt, short* __restrict__ Wvt,
    short* __restrict__ Wfh, short* __restrict__ Wfl,
    short* __restrict__ pe_kb, short* __restrict__ pe_vt)
{
    int z = blockIdx.x, tid = threadIdx.x;
    if (z == 1024) {
        for (int s = tid; s < 144 * 64; s += 256) {
            int j = s >> 6, d = s & 63;
            pe_kb[s] = (j < 129) ? f2b(pe_k[j * 64 + d]) : (short)0;
        }
        for (int s = tid; s < 64 * 160; s += 256) {
            int d = s / 160, j = s - d * 160;
            pe_vt[s] = (j < 129) ? f2b(pe_v[j * 64 + d]) : (short)0;
        }
        return;
    }
    __shared__ float T[64][65];
    const float* src; short* dhi; short* dlo = nullptr;
    int C, c0, r0; float scale = 1.f;
    if (z < 768) {
        int widx = z >> 8, rem = z & 255;
        int h = rem >> 4, rt = rem & 15;
        src = (widx == 0 ? Wq : widx == 1 ? Wk : Wv) + (size_t)h * 1024 * 64;
        dhi = (widx == 0 ? Wqt : widx == 1 ? Wkt : Wvt) + (size_t)h * 64 * 1024;
        scale = (widx == 0) ? 0.125f * LOG2E : 1.0f;
        C = 64; c0 = 0; r0 = rt * 64;
    } else {
        int idx = z - 768;
        src = Wfc; dhi = Wfh; dlo = Wfl;
        C = 1024; c0 = (idx >> 4) * 64; r0 = (idx & 15) * 64;
    }
#pragma unroll
    for (int i = 0; i < 4; ++i) {
        int slot = tid + i * 256;
        int r = slot >> 4, cg = (slot & 15) * 4;
        float4 v = *(const float4*)(src + (size_t)(r0 + r) * C + c0 + cg);
        T[r][cg+0] = v.x*scale; T[r][cg+1] = v.y*scale;
        T[r][cg+2] = v.z*scale; T[r][cg+3] = v.w*scale;
    }
    __syncthreads();
#pragma unroll
    for (int i = 0; i < 16; ++i) {
        int slot = tid + i * 256;
        int c = slot >> 6, r = slot & 63;
        float v = T[r][c];
        short hi = f2b(v);
        size_t o = (size_t)(c0 + c) * 1024 + r0 + r;
        dhi[o] = hi;
        if (dlo) dlo[o] = f2b(v - b2f(hi));
    }
}

// ---------------------------------------------------------------------------
// shared GEMM core: 128x128 tile, BK=64, global_load_lds staging (r4-proven)
__device__ __forceinline__ void gemm_core(
    const short* __restrict__ Ahi, const short* __restrict__ Alo,
    const short* __restrict__ Bhi, const short* __restrict__ Blo,
    int kIters, int m0, int n0, short* As, short* Bs, f32x4 (&acc)[4][4])
{
    const int tid = threadIdx.x, w = tid >> 6, lane = tid & 63;
    const int l15 = lane & 15, lr4 = lane >> 4;
    const int wr = w >> 1, wc = w & 1;

    for (int it = 0; it < kIters; ++it) {
        int kt = it * 64;
        int seg = kt >> 10, kk0 = kt & 1023;
        const short* Aseg = (seg == 1) ? Alo : Ahi;
        const short* Bseg = (seg == 2) ? Blo : Bhi;
        __syncthreads();
#pragma unroll
        for (int c = 0; c < 4; ++c) {
            int slot = (w * 4 + c) * 64 + lane;
            int r = slot >> 3, cb = slot & 7;
            int sm = m0 + r; sm = sm < M_ ? sm : M_ - 1;
            gload16(Aseg + (size_t)sm * 1024 + kk0 + ((cb ^ (r & 7)) * 8),
                    As + (size_t)(w * 4 + c) * 512);
            gload16(Bseg + (size_t)(n0 + r) * 1024 + kk0 + ((cb ^ (r & 7)) * 8),
                    Bs + (size_t)(w * 4 + c) * 512);
        }
        __syncthreads();
#pragma unroll
        for (int kh = 0; kh < 2; ++kh) {
            bf16x8 aF[4], bF[4];
#pragma unroll
            for (int mi = 0; mi < 4; ++mi) {
                int r = wr * 64 + mi * 16 + l15;
                aF[mi] = *(const bf16x8*)(As + r * 64 + (((kh*4+lr4) ^ (r & 7)) * 8));
            }
#pragma unroll
            for (int ni = 0; ni < 4; ++ni) {
                int r = wc * 64 + ni * 16 + l15;
                bF[ni] = *(const bf16x8*)(Bs + r * 64 + (((kh*4+lr4) ^ (r & 7)) * 8));
            }
#pragma unroll
            for (int mi = 0; mi < 4; ++mi)
#pragma unroll
                for (int ni = 0; ni < 4; ++ni)
                    acc[mi][ni] = __builtin_amdgcn_mfma_f32_16x16x32_bf16(
                        aF[mi], bF[ni], acc[mi][ni], 0, 0, 0);
        }
    }
}

// QKV projections, one launch (grid.z selects)
__global__ __launch_bounds__(256) void gemm_qkv(
    const short* __restrict__ qb, const short* __restrict__ kb,
    const short* __restrict__ vb, const short* __restrict__ Wqt,
    const short* __restrict__ Wkt, const short* __restrict__ Wvt,
    const float* __restrict__ bq, const float* __restrict__ bk,
    const float* __restrict__ bv,
    short* __restrict__ Qp, short* __restrict__ Kp, short* __restrict__ Vp)
{
    __shared__ short As[128 * 64];
    __shared__ short Bs[128 * 64];
    const int z = blockIdx.z;
    const short* A  = z == 0 ? qb : z == 1 ? kb : vb;
    const short* Bw = z == 0 ? Wqt : z == 1 ? Wkt : Wvt;
    const float* bias = z == 0 ? bq : z == 1 ? bk : bv;
    const float bscale = z == 0 ? 0.125f * LOG2E : 1.0f;
    short* out = z == 0 ? Qp : z == 1 ? Kp : Vp;
    const int m0 = blockIdx.x * 128, n0 = blockIdx.y * 128;

    f32x4 zf = {0.f,0.f,0.f,0.f};
    f32x4 acc[4][4];
#pragma unroll
    for (int i = 0; i < 4; ++i)
#pragma unroll
        for (int j = 0; j < 4; ++j) acc[i][j] = zf;

    gemm_core(A, A, Bw, Bw, 16, m0, n0, As, Bs, acc);

    const int tid = threadIdx.x, w = tid >> 6, lane = tid & 63;
    const int l15 = lane & 15, lr4 = lane >> 4;
    const int wr = w >> 1, wc = w & 1;
#pragma unroll
    for (int mi = 0; mi < 4; ++mi)
#pragma unroll
        for (int rr = 0; rr < 4; ++rr) {
            int m = m0 + wr * 64 + mi * 16 + lr4 * 4 + rr;
            if (m >= M_) continue;
            int b = m / S_, s = m - b * S_;
#pragma unroll
            for (int ni = 0; ni < 4; ++ni) {
                int n = n0 + wc * 64 + ni * 16 + l15;
                float v = acc[mi][ni][rr] + bias[n] * bscale;
                int h = n >> 6, d = n & 63;
                out[(((size_t)(b * NH_ + h)) * S_ + s) * HD_ + d] = f2b(v);
            }
        }
}

// final projection, 3-segment split-bf16, f32 out
__global__ __launch_bounds__(256) void gemm_fc(
    const short* __restrict__ Ahi, const short* __restrict__ Alo,
    const short* __restrict__ Bhi, const short* __restrict__ Blo,
    const float* __restrict__ bias, float* __restrict__ out)
{
    __shared__ short As[128 * 64];
    __shared__ short Bs[128 * 64];
    const int m0 = blockIdx.x * 128, n0 = blockIdx.y * 128;
    f32x4 zf = {0.f,0.f,0.f,0.f};
    f32x4 acc[4][4];
#pragma unroll
    for (int i = 0; i < 4; ++i)
#pragma unroll
        for (int j = 0; j < 4; ++j) acc[i][j] = zf;

    gemm_core(Ahi, Alo, Bhi, Blo, 48, m0, n0, As, Bs, acc);

    const int tid = threadIdx.x, w = tid >> 6, lane = tid & 63;
    const int l15 = lane & 15, lr4 = lane >> 4;
    const int wr = w >> 1, wc = w & 1;
#pragma unroll
    for (int mi = 0; mi < 4; ++mi)
#pragma unroll
        for (int rr = 0; rr < 4; ++rr) {
            int m = m0 + wr * 64 + mi * 16 + lr4 * 4 + rr;
            if (m >= M_) continue;
#pragma unroll
            for (int ni = 0; ni < 4; ++ni) {
                int n = n0 + wc * 64 + ni * 16 + l15;
                out[(size_t)m * 1024 + n] = acc[mi][ni][rr] + bias[n];
            }
        }
}

// ---------------------------------------------------------------------------
// V panel transpose: [bh][s][d] -> [bh][d][SP_]   (r4-proven, no permutation)
__global__ __launch_bounds__(256) void vtrans(
    const short* __restrict__ Vp, short* __restrict__ Vtg)
{
    __shared__ short T[64][72];
    const int bh = blockIdx.y, s0 = blockIdx.x * 64, tid = threadIdx.x;
    const size_t kv = (size_t)bh * S_ * 64;
#pragma unroll
    for (int i = 0; i < 2; ++i) {
        int slot = tid + i * 256;
        int r = slot >> 3, cb = slot & 7;
        int ss = s0 + r; ss = ss < S_ ? ss : S_ - 1;
        bf16x8 v = *(const bf16x8*)(Vp + kv + (size_t)ss * 64 + cb * 8);
        *(bf16x8*)(&T[r][cb * 8]) = v;
    }
    __syncthreads();
#pragma unroll
    for (int i = 0; i < 2; ++i) {
        int slot = tid + i * 256;
        int d = slot >> 3, cg = slot & 7;
        bf16x8 v;
#pragma unroll
        for (int j = 0; j < 8; ++j) v[j] = T[cg * 8 + j][d];
        *(bf16x8*)(Vtg + ((size_t)bh * 64 + d) * SP_ + s0 + cg * 8) = v;
    }
}

// ---------------------------------------------------------------------------
// Fused flash attention: r3-proven single-buffer loop skeleton (2 barriers
// per chunk, SEPARATE Pw buffer, qpe@144, wsm@160, K=160 bias MFMA) combined
// with r4-proven features (exp2 domain, defer-max, XCD swizzle, setprio).
// LDS = 62 KB, no aliasing, no inline waitcnt.
__global__ __launch_bounds__(256) void attn_mfma(
    const short* __restrict__ Qb, const short* __restrict__ Kb,
    const short* __restrict__ Vtg, const short* __restrict__ pe_kb,
    const short* __restrict__ pe_vt,
    short* __restrict__ hid_hi, short* __restrict__ hid_lo)
{
    __shared__ short Kc[4096];        // K chunk (Q in prologue)
    __shared__ short Vt[4096];        // V^T chunk [d][k]
    __shared__ short qpe[64 * 144];   // [row][j] Shaw key-bias (log2 domain)
    __shared__ short wsm[64 * 160];   // [row][j] raw band logits -> e-values
    __shared__ short Pw[4][1024];     // per-wave P, XOR-swizzled qwords

    const int tid = threadIdx.x, w = tid >> 6, lane = tid & 63;
    const int l15 = lane & 15, lr4 = lane >> 4;
    const int lg = (blockIdx.x & 7) * 96 + (blockIdx.x >> 3);   // XCD swizzle
    const int bh = lg / 24, bx = lg - bh * 24;
    const int q0 = bx * 64;
    const int qw = q0 + w * 16;
    const int myq = qw + l15;           // lane's q row
    const int myrow = w * 16 + l15;     // LDS row
    const size_t kv  = (size_t)bh * S_ * HD_;
    const size_t vtb = (size_t)bh * 64 * SP_;
    const int swz = (l15 & 7) << 1;

    // init wsm rows (wave-local) to -1e30
    {
        short ini = f2b(-1e30f);
        bf16x8 iv;
#pragma unroll
        for (int i = 0; i < 8; ++i) iv[i] = ini;
        short* base = wsm + w * 16 * 160;
#pragma unroll
        for (int i = 0; i < 5; ++i)
            *(bf16x8*)(base + (size_t)(i * 64 + lane) * 8) = iv;
    }
    // stage Q -> Kc (pre-swizzled source, linear dest)
#pragma unroll
    for (int cc = 0; cc < 2; ++cc) {
        int slot = (w * 2 + cc) * 64 + lane;
        int r = slot >> 3, cb = slot & 7;
        int sq = q0 + r; sq = sq < S_ ? sq : S_ - 1;
        gload16(Qb + kv + (size_t)sq * 64 + ((cb ^ (r & 7)) * 8),
                Kc + (size_t)(w * 2 + cc) * 512);
    }
    __syncthreads();

    bf16x8 qA[2];
    {
        int r = myrow;
        qA[0] = *(const bf16x8*)(Kc + r * 64 + ((lr4 ^ (r & 7)) * 8));
        qA[1] = *(const bf16x8*)(Kc + r * 64 + (((4 + lr4) ^ (r & 7)) * 8));
    }

    // qpe: D[j][q] = pe_k . Q (log2 domain via Wq scale); full 9-tile write
    f32x4 zf = {0.f,0.f,0.f,0.f};
#pragma unroll
    for (int jt = 0; jt < 9; ++jt) {
        f32x4 a = zf;
#pragma unroll
        for (int kh = 0; kh < 2; ++kh) {
            bf16x8 pf = *(const bf16x8*)(pe_kb + (size_t)(jt * 16 + l15) * 64 + kh * 32 + lr4 * 8);
            a = __builtin_amdgcn_mfma_f32_16x16x32_bf16(pf, qA[kh], a, 0, 0, 0);
        }
        bf16x4 pk;
#pragma unroll
        for (int rr = 0; rr < 4; ++rr) pk[rr] = f2b(a[rr]);
        *(bf16x4*)(qpe + (size_t)myrow * 144 + jt * 16 + lr4 * 4) = pk;
    }
    const float qpe0   = b2f(qpe[myrow * 144 + 0]);
    const float qpe128 = b2f(qpe[myrow * 144 + 128]);
    __syncthreads();   // all waves done reading Kc (Q)

    float m = -1e30f, s0s = 0.f, s1s = 0.f;
    f32x4 o[4];
#pragma unroll
    for (int t = 0; t < 4; ++t) o[t] = zf;

    for (int c = 0; c < 24; ++c) {
        const int kc = c * 64;
        // stage K + V^T (single buffer)
#pragma unroll
        for (int cc = 0; cc < 2; ++cc) {
            int slot = (w * 2 + cc) * 64 + lane;
            int r = slot >> 3, cb = slot & 7;
            int sk = kc + r; sk = sk < S_ ? sk : S_ - 1;
            gload16(Kb + kv + (size_t)sk * 64 + ((cb ^ (r & 7)) * 8),
                    Kc + (size_t)(w * 2 + cc) * 512);
            gload16(Vtg + vtb + (size_t)r * SP_ + kc + ((cb ^ (r & 7)) * 8),
                    Vt + (size_t)(w * 2 + cc) * 512);
        }
        __syncthreads();   // staging complete (syncthreads drains vmcnt)

        // swapped QK^T: sa[t][rr] = S[q=myq][k=kc+t*16+lr4*4+rr]
        __builtin_amdgcn_s_setprio(1);
        f32x4 sa[4];
#pragma unroll
        for (int t = 0; t < 4; ++t) {
            sa[t] = zf;
#pragma unroll
            for (int kh = 0; kh < 2; ++kh) {
                int r = t * 16 + l15;
                bf16x8 kB = *(const bf16x8*)(Kc + r * 64 + (((kh*4+lr4) ^ (r & 7)) * 8));
                sa[t] = __builtin_amdgcn_mfma_f32_16x16x32_bf16(kB, qA[kh], sa[t], 0, 0, 0);
            }
        }
        __builtin_amdgcn_s_setprio(0);

        const bool all_lo = (kc + 63 - qw) <= -64;
        const bool all_hi = (kc - (qw + 15)) >= 64;
        const bool mixed  = !(all_lo || all_hi);
        const float ubias = all_lo ? qpe0 : qpe128;

        float lg2[4][4];
        float rm = -1e30f;
#pragma unroll
        for (int t = 0; t < 4; ++t)
#pragma unroll
            for (int rr = 0; rr < 4; ++rr) {
                int k = kc + t * 16 + lr4 * 4 + rr;
                int rel = k - myq;
                float v;
                if (mixed) {
                    int jc = rel < -64 ? 0 : (rel > 64 ? 128 : rel + 64);
                    v = sa[t][rr] + b2f(qpe[myrow * 144 + jc]);
                } else {
                    v = sa[t][rr] + ubias;
                }
                if (k >= S_) v = -1e30f;
                lg2[t][rr] = v;
                rm = fmaxf(rm, v);
                if (mixed && rel > -64 && rel < 64)
                    wsm[myrow * 160 + rel + 64] = f2b(v);
            }
        rm = fmaxf(rm, __shfl_xor(rm, 16));
        rm = fmaxf(rm, __shfl_xor(rm, 32));

        // defer-max: only rescale when growth exceeds 8 (log2 domain)
        if (!__all(rm <= m + 8.f)) {
            float nm = fmaxf(m, rm);
            float fac = exp2f(m - nm);
            m = nm; s0s *= fac; s1s *= fac;
            float fo[4];
#pragma unroll
            for (int rr = 0; rr < 4; ++rr) fo[rr] = __shfl(fac, lr4 * 4 + rr);
#pragma unroll
            for (int t = 0; t < 4; ++t)
#pragma unroll
                for (int rr = 0; rr < 4; ++rr) o[t][rr] *= fo[rr];
        }

        // p = exp2, bucket partials, vectorized P writes into Pw[w]
        float ls0 = 0.f, ls1 = 0.f;
#pragma unroll
        for (int t = 0; t < 4; ++t) {
            bf16x4 pk;
#pragma unroll
            for (int rr = 0; rr < 4; ++rr) {
                float p2 = exp2f(lg2[t][rr] - m);
                pk[rr] = f2b(p2);
                if (mixed) {
                    int rel = (kc + t * 16 + lr4 * 4 + rr) - myq;
                    if (rel <= -64) ls0 += p2; else if (rel >= 64) ls1 += p2;
                } else if (all_lo) ls0 += p2; else ls1 += p2;
            }
            *(bf16x4*)(Pw[w] + l15 * 64 + (((t * 4 + lr4) ^ swz) << 2)) = pk;
        }
        ls0 += __shfl_xor(ls0, 16); ls0 += __shfl_xor(ls0, 32);
        ls1 += __shfl_xor(ls1, 16); ls1 += __shfl_xor(ls1, 32);
        s0s += ls0; s1s += ls1;

        // PV (P from wave-private Pw[w], V from Vt)
        __builtin_amdgcn_s_setprio(1);
#pragma unroll
        for (int win = 0; win < 2; ++win) {
            bf16x8 pA = *(const bf16x8*)(Pw[w] + l15 * 64 + (((win * 8 + lr4 * 2) ^ swz) << 2));
#pragma unroll
            for (int td = 0; td < 4; ++td) {
                int r = td * 16 + l15;
                bf16x8 vB = *(const bf16x8*)(Vt + r * 64 + (((win*4+lr4) ^ (r & 7)) * 8));
                o[td] = __builtin_amdgcn_mfma_f32_16x16x32_bf16(pA, vB, o[td], 0, 0, 0);
            }
        }
        __builtin_amdgcn_s_setprio(0);

        __syncthreads();   // all reads of Kc/Vt done; next iter may restage
    }

    // ---- epilogue (r4-exact, wave-local wsm traffic) ----
    short* rowp = wsm + (size_t)myrow * 160;
    float midsum = 0.f;
#pragma unroll
    for (int cc = 0; cc < 5; ++cc) {
        int off = (cc * 4 + lr4) * 8;
        bf16x8 mv = *(const bf16x8*)(rowp + off);
        bf16x8 ev;
#pragma unroll
        for (int jj = 0; jj < 8; ++jj) {
            float e = exp2f(b2f(mv[jj]) - m);
            ev[jj] = f2b(e);
            midsum += e;
        }
        *(bf16x8*)(rowp + off) = ev;
    }
    midsum += __shfl_xor(midsum, 16); midsum += __shfl_xor(midsum, 32);
    const float linv = 1.f / (s0s + s1s + midsum);
    if (lr4 == 0) { rowp[0] = f2b(s0s); rowp[128] = f2b(s1s); }

    // o += wsm-row . pe_v^T  (K = 160)
#pragma unroll
    for (int jh = 0; jh < 5; ++jh) {
        bf16x8 aW = *(const bf16x8*)(wsm + (size_t)myrow * 160 + jh * 32 + lr4 * 8);
#pragma unroll
        for (int td = 0; td < 4; ++td) {
            bf16x8 bW = *(const bf16x8*)(pe_vt + (size_t)(td * 16 + l15) * 160 + jh * 32 + lr4 * 8);
            o[td] = __builtin_amdgcn_mfma_f32_16x16x32_bf16(aW, bW, o[td], 0, 0, 0);
        }
    }

    // normalize (o rows = lr4*4+rr; inv lives on lane lr4*4+rr)
    {
        float fo[4];
#pragma unroll
        for (int rr = 0; rr < 4; ++rr) fo[rr] = __shfl(linv, lr4 * 4 + rr);
#pragma unroll
        for (int td = 0; td < 4; ++td)
#pragma unroll
            for (int rr = 0; rr < 4; ++rr) o[td][rr] *= fo[rr];
    }

    // stage hi -> Pw[w], lo -> wsm rows (both wave-local), then b128 stores
#pragma unroll
    for (int td = 0; td < 4; ++td)
#pragma unroll
        for (int rr = 0; rr < 4; ++rr) {
            int qrow = lr4 * 4 + rr;
            int d = td * 16 + l15;
            int inner = (((d >> 2) ^ ((qrow & 7) << 1)) << 2) + (d & 3);
            float v = o[td][rr];
            short hi = f2b(v);
            Pw[w][qrow * 64 + inner] = hi;
            wsm[(w * 16 + qrow) * 160 + inner] = f2b(v - b2f(hi));
        }
    {
        int b = bh >> 4, h = bh & 15;
        int qrow = lane >> 2;
        int q = q0 + w * 16 + qrow;
#pragma unroll
        for (int i = 0; i < 2; ++i) {
            int cb = (lane & 3) * 2 + i;
            int qws = (cb * 2) ^ ((qrow & 7) << 1);
            bf16x8 hv = *(const bf16x8*)(Pw[w] + qrow * 64 + qws * 4);
            bf16x8 lv = *(const bf16x8*)(wsm + (w * 16 + qrow) * 160 + qws * 4);
            if (q < S_) {
                size_t oo = ((size_t)(b * S_ + q)) * 1024 + h * 64 + cb * 8;
                *(bf16x8*)(hid_hi + oo) = hv;
                *(bf16x8*)(hid_lo + oo) = lv;
            }
        }
    }
}

// ---------------------------------------------------------------------------
extern "C" void kernel_launch(void* const* d_in, const int* in_sizes, int n_in,
                              void* d_out, int out_size, void* d_ws, size_t ws_size,
                              hipStream_t stream)
{
    const float* query = (const float*)d_in[0];
    const float* key   = (const float*)d_in[1];
    const float* value = (const float*)d_in[2];
    const float* Wq    = (const float*)d_in[3];
    const float* bq    = (const float*)d_in[4];
    const float* Wk    = (const float*)d_in[5];
    const float* bk    = (const float*)d_in[6];
    const float* Wv    = (const float*)d_in[7];
    const float* bv    = (const float*)d_in[8];
    const float* pe_k  = (const float*)d_in[9];
    const float* pe_v  = (const float*)d_in[10];
    const float* W_fc  = (const float*)d_in[11];
    const float* b_fc  = (const float*)d_in[12];

    char* W = (char*)d_ws;
    short* qb   = (short*)(W + 0);          // later: hid_hi
    short* kb   = (short*)(W + 6291456);    // later: hid_lo
    short* vb   = (short*)(W + 12582912);   // later: Vtg (transposed V)
    short* Vtg  = vb;
    short* Wqt  = (short*)(W + 18874368);
    short* Wkt  = (short*)(W + 20971520);
    short* Wvt  = (short*)(W + 23068672);
    short* Wfh  = (short*)(W + 25165824);
    short* Wfl  = (short*)(W + 27262976);
    short* Qp   = (short*)(W + 29360128);
    short* Kp   = (short*)(W + 35651584);
    short* Vp   = (short*)(W + 41943040);
    short* pekb = (short*)(W + 48234496);
    short* pevt = (short*)(W + 48252928);
    short* hidh = qb;
    short* hidl = kb;

    cvt_act3<<<dim3(1500, 3), 256, 0, stream>>>(query, key, value, qb, kb, vb);
    prep_w<<<1025, 256, 0, stream>>>(Wq, Wk, Wv, W_fc, pe_k, pe_v,
                                     Wqt, Wkt, Wvt, Wfh, Wfl, pekb, pevt);
    gemm_qkv<<<dim3(24, 8, 3), 256, 0, stream>>>(qb, kb, vb, Wqt, Wkt, Wvt,
                                                 bq, bk, bv, Qp, Kp, Vp);
    vtrans<<<dim3(24, 32), 256, 0, stream>>>(Vp, Vtg);
    attn_mfma<<<768, 256, 0, stream>>>(Qp, Kp, Vtg, pekb, pevt, hidh, hidl);
    gemm_fc<<<dim3(24, 8), 256, 0, stream>>>(hidh, hidl, Wfh, Wfl, b_fc, (float*)d_out);
}

// Round 8
// 279.269 us; speedup vs baseline: 1.0356x; 1.0356x over previous
//
#include <hip/hip_runtime.h>
#include <math.h>

#define B_     2
#define S_     1500
#define HID_   1024
#define NH_    16
#define HD_    64
#define M_     (B_*S_)   // 3000
#define SP_    1536      // padded S for transposed-V rows
#define LOG2E  1.4426950408889634f

typedef short bf16x8 __attribute__((ext_vector_type(8)));
typedef short bf16x4 __attribute__((ext_vector_type(4)));
typedef float f32x4  __attribute__((ext_vector_type(4)));

__device__ __forceinline__ float b2f(short s) {
    unsigned u = ((unsigned)(unsigned short)s) << 16;
    return __uint_as_float(u);
}
__device__ __forceinline__ short f2b(float f) {   // RNE, finite inputs
    unsigned u = __float_as_uint(f);
    unsigned r = (u + 0x7FFFu + ((u >> 16) & 1u)) >> 16;
    return (short)r;
}
__device__ __forceinline__ void gload16(const short* src, short* lds) {
    __builtin_amdgcn_global_load_lds(
        (const __attribute__((address_space(1))) void*)src,
        (__attribute__((address_space(3))) void*)lds, 16, 0, 0);
}

// ---------------------------------------------------------------------------
// f32 -> bf16 for the three activations, one launch
__global__ __launch_bounds__(256) void cvt_act3(
    const float* __restrict__ q, const float* __restrict__ k,
    const float* __restrict__ v, short* __restrict__ oq,
    short* __restrict__ ok, short* __restrict__ ov)
{
    const float* src = blockIdx.y == 0 ? q : blockIdx.y == 1 ? k : v;
    short* dst       = blockIdx.y == 0 ? oq : blockIdx.y == 1 ? ok : ov;
    int i = blockIdx.x * 256 + threadIdx.x;      // < 384000
    const float4* p = (const float4*)(src + (size_t)i * 8);
    float4 a = p[0], b = p[1];
    bf16x8 o;
    o[0]=f2b(a.x); o[1]=f2b(a.y); o[2]=f2b(a.z); o[3]=f2b(a.w);
    o[4]=f2b(b.x); o[5]=f2b(b.y); o[6]=f2b(b.z); o[7]=f2b(b.w);
    *(bf16x8*)(dst + (size_t)i * 8) = o;
}

// ---------------------------------------------------------------------------
// all weight prep in one launch; Wq/bq fold 0.125*log2e
__global__ __launch_bounds__(256) void prep_w(
    const float* __restrict__ Wq, const float* __restrict__ Wk,
    const float* __restrict__ Wv, const float* __restrict__ Wfc,
    const float* __restrict__ pe_k, const float* __restrict__ pe_v,
    short* __restrict__ Wqt, short* __restrict__ Wkt, short* __restrict__ Wvt,
    short* __restrict__ Wfh, short* __restrict__ Wfl,
    short* __restrict__ pe_kb, short* __restrict__ pe_vt)
{
    int z = blockIdx.x, tid = threadIdx.x;
    if (z == 1024) {
        for (int s = tid; s < 144 * 64; s += 256) {
            int j = s >> 6, d = s & 63;
            pe_kb[s] = (j < 129) ? f2b(pe_k[j * 64 + d]) : (short)0;
        }
        for (int s = tid; s < 64 * 160; s += 256) {
            int d = s / 160, j = s - d * 160;
            pe_vt[s] = (j < 129) ? f2b(pe_v[j * 64 + d]) : (short)0;
        }
        return;
    }
    __shared__ float T[64][65];
    const float* src; short* dhi; short* dlo = nullptr;
    int C, c0, r0; float scale = 1.f;
    if (z < 768) {
        int widx = z >> 8, rem = z & 255;
        int h = rem >> 4, rt = rem & 15;
        src = (widx == 0 ? Wq : widx == 1 ? Wk : Wv) + (size_t)h * 1024 * 64;
        dhi = (widx == 0 ? Wqt : widx == 1 ? Wkt : Wvt) + (size_t)h * 64 * 1024;
        scale = (widx == 0) ? 0.125f * LOG2E : 1.0f;
        C = 64; c0 = 0; r0 = rt * 64;
    } else {
        int idx = z - 768;
        src = Wfc; dhi = Wfh; dlo = Wfl;
        C = 1024; c0 = (idx >> 4) * 64; r0 = (idx & 15) * 64;
    }
#pragma unroll
    for (int i = 0; i < 4; ++i) {
        int slot = tid + i * 256;
        int r = slot >> 4, cg = (slot & 15) * 4;
        float4 v = *(const float4*)(src + (size_t)(r0 + r) * C + c0 + cg);
        T[r][cg+0] = v.x*scale; T[r][cg+1] = v.y*scale;
        T[r][cg+2] = v.z*scale; T[r][cg+3] = v.w*scale;
    }
    __syncthreads();
#pragma unroll
    for (int i = 0; i < 16; ++i) {
        int slot = tid + i * 256;
        int c = slot >> 6, r = slot & 63;
        float v = T[r][c];
        short hi = f2b(v);
        size_t o = (size_t)(c0 + c) * 1024 + r0 + r;
        dhi[o] = hi;
        if (dlo) dlo[o] = f2b(v - b2f(hi));
    }
}

// ---------------------------------------------------------------------------
// shared GEMM core: 128x128 tile, BK=64, global_load_lds staging (r4-proven)
__device__ __forceinline__ void gemm_core(
    const short* __restrict__ Ahi, const short* __restrict__ Alo,
    const short* __restrict__ Bhi, const short* __restrict__ Blo,
    int kIters, int m0, int n0, short* As, short* Bs, f32x4 (&acc)[4][4])
{
    const int tid = threadIdx.x, w = tid >> 6, lane = tid & 63;
    const int l15 = lane & 15, lr4 = lane >> 4;
    const int wr = w >> 1, wc = w & 1;

    for (int it = 0; it < kIters; ++it) {
        int kt = it * 64;
        int seg = kt >> 10, kk0 = kt & 1023;
        const short* Aseg = (seg == 1) ? Alo : Ahi;
        const short* Bseg = (seg == 2) ? Blo : Bhi;
        __syncthreads();
#pragma unroll
        for (int c = 0; c < 4; ++c) {
            int slot = (w * 4 + c) * 64 + lane;
            int r = slot >> 3, cb = slot & 7;
            int sm = m0 + r; sm = sm < M_ ? sm : M_ - 1;
            gload16(Aseg + (size_t)sm * 1024 + kk0 + ((cb ^ (r & 7)) * 8),
                    As + (size_t)(w * 4 + c) * 512);
            gload16(Bseg + (size_t)(n0 + r) * 1024 + kk0 + ((cb ^ (r & 7)) * 8),
                    Bs + (size_t)(w * 4 + c) * 512);
        }
        __syncthreads();
#pragma unroll
        for (int kh = 0; kh < 2; ++kh) {
            bf16x8 aF[4], bF[4];
#pragma unroll
            for (int mi = 0; mi < 4; ++mi) {
                int r = wr * 64 + mi * 16 + l15;
                aF[mi] = *(const bf16x8*)(As + r * 64 + (((kh*4+lr4) ^ (r & 7)) * 8));
            }
#pragma unroll
            for (int ni = 0; ni < 4; ++ni) {
                int r = wc * 64 + ni * 16 + l15;
                bF[ni] = *(const bf16x8*)(Bs + r * 64 + (((kh*4+lr4) ^ (r & 7)) * 8));
            }
#pragma unroll
            for (int mi = 0; mi < 4; ++mi)
#pragma unroll
                for (int ni = 0; ni < 4; ++ni)
                    acc[mi][ni] = __builtin_amdgcn_mfma_f32_16x16x32_bf16(
                        aF[mi], bF[ni], acc[mi][ni], 0, 0, 0);
        }
    }
}

// QKV projections, one launch (grid.z selects)
__global__ __launch_bounds__(256) void gemm_qkv(
    const short* __restrict__ qb, const short* __restrict__ kb,
    const short* __restrict__ vb, const short* __restrict__ Wqt,
    const short* __restrict__ Wkt, const short* __restrict__ Wvt,
    const float* __restrict__ bq, const float* __restrict__ bk,
    const float* __restrict__ bv,
    short* __restrict__ Qp, short* __restrict__ Kp, short* __restrict__ Vp)
{
    __shared__ short As[128 * 64];
    __shared__ short Bs[128 * 64];
    const int z = blockIdx.z;
    const short* A  = z == 0 ? qb : z == 1 ? kb : vb;
    const short* Bw = z == 0 ? Wqt : z == 1 ? Wkt : Wvt;
    const float* bias = z == 0 ? bq : z == 1 ? bk : bv;
    const float bscale = z == 0 ? 0.125f * LOG2E : 1.0f;
    short* out = z == 0 ? Qp : z == 1 ? Kp : Vp;
    const int m0 = blockIdx.x * 128, n0 = blockIdx.y * 128;

    f32x4 zf = {0.f,0.f,0.f,0.f};
    f32x4 acc[4][4];
#pragma unroll
    for (int i = 0; i < 4; ++i)
#pragma unroll
        for (int j = 0; j < 4; ++j) acc[i][j] = zf;

    gemm_core(A, A, Bw, Bw, 16, m0, n0, As, Bs, acc);

    const int tid = threadIdx.x, w = tid >> 6, lane = tid & 63;
    const int l15 = lane & 15, lr4 = lane >> 4;
    const int wr = w >> 1, wc = w & 1;
#pragma unroll
    for (int mi = 0; mi < 4; ++mi)
#pragma unroll
        for (int rr = 0; rr < 4; ++rr) {
            int m = m0 + wr * 64 + mi * 16 + lr4 * 4 + rr;
            if (m >= M_) continue;
            int b = m / S_, s = m - b * S_;
#pragma unroll
            for (int ni = 0; ni < 4; ++ni) {
                int n = n0 + wc * 64 + ni * 16 + l15;
                float v = acc[mi][ni][rr] + bias[n] * bscale;
                int h = n >> 6, d = n & 63;
                out[(((size_t)(b * NH_ + h)) * S_ + s) * HD_ + d] = f2b(v);
            }
        }
}

// final projection, 3-segment split-bf16, f32 out
__global__ __launch_bounds__(256) void gemm_fc(
    const short* __restrict__ Ahi, const short* __restrict__ Alo,
    const short* __restrict__ Bhi, const short* __restrict__ Blo,
    const float* __restrict__ bias, float* __restrict__ out)
{
    __shared__ short As[128 * 64];
    __shared__ short Bs[128 * 64];
    const int m0 = blockIdx.x * 128, n0 = blockIdx.y * 128;
    f32x4 zf = {0.f,0.f,0.f,0.f};
    f32x4 acc[4][4];
#pragma unroll
    for (int i = 0; i < 4; ++i)
#pragma unroll
        for (int j = 0; j < 4; ++j) acc[i][j] = zf;

    gemm_core(Ahi, Alo, Bhi, Blo, 48, m0, n0, As, Bs, acc);

    const int tid = threadIdx.x, w = tid >> 6, lane = tid & 63;
    const int l15 = lane & 15, lr4 = lane >> 4;
    const int wr = w >> 1, wc = w & 1;
#pragma unroll
    for (int mi = 0; mi < 4; ++mi)
#pragma unroll
        for (int rr = 0; rr < 4; ++rr) {
            int m = m0 + wr * 64 + mi * 16 + lr4 * 4 + rr;
            if (m >= M_) continue;
#pragma unroll
            for (int ni = 0; ni < 4; ++ni) {
                int n = n0 + wc * 64 + ni * 16 + l15;
                out[(size_t)m * 1024 + n] = acc[mi][ni][rr] + bias[n];
            }
        }
}

// ---------------------------------------------------------------------------
// V panel transpose: [bh][s][d] -> [bh][d][SP_]   (r4-proven, no permutation)
__global__ __launch_bounds__(256) void vtrans(
    const short* __restrict__ Vp, short* __restrict__ Vtg)
{
    __shared__ short T[64][72];
    const int bh = blockIdx.y, s0 = blockIdx.x * 64, tid = threadIdx.x;
    const size_t kv = (size_t)bh * S_ * 64;
#pragma unroll
    for (int i = 0; i < 2; ++i) {
        int slot = tid + i * 256;
        int r = slot >> 3, cb = slot & 7;
        int ss = s0 + r; ss = ss < S_ ? ss : S_ - 1;
        bf16x8 v = *(const bf16x8*)(Vp + kv + (size_t)ss * 64 + cb * 8);
        *(bf16x8*)(&T[r][cb * 8]) = v;
    }
    __syncthreads();
#pragma unroll
    for (int i = 0; i < 2; ++i) {
        int slot = tid + i * 256;
        int d = slot >> 3, cg = slot & 7;
        bf16x8 v;
#pragma unroll
        for (int j = 0; j < 8; ++j) v[j] = T[cg * 8 + j][d];
        *(bf16x8*)(Vtg + ((size_t)bh * 64 + d) * SP_ + s0 + cg * 8) = v;
    }
}

// ---------------------------------------------------------------------------
// Fused flash attention: r7-proven phases, KVBLK=128 (12 chunks, processed as
// two 64-halves per chunk; 2 barriers per 128 k instead of per 64).
// LDS = 78 KB -> still 2 blocks/CU; halves the barrier/drain count.
__global__ __launch_bounds__(256) void attn_mfma(
    const short* __restrict__ Qb, const short* __restrict__ Kb,
    const short* __restrict__ Vtg, const short* __restrict__ pe_kb,
    const short* __restrict__ pe_vt,
    short* __restrict__ hid_hi, short* __restrict__ hid_lo)
{
    __shared__ short Kc[128 * 64];    // K chunk [k=128][d=64] (Q in prologue)
    __shared__ short Vt[64 * 128];    // V^T chunk [d=64][k=128]
    __shared__ short qpe[64 * 144];   // [row][j] Shaw key-bias (log2 domain)
    __shared__ short wsm[64 * 160];   // [row][j] raw band logits -> e-values
    __shared__ short Pw[4][1024];     // per-wave P (16x64, one half at a time)

    const int tid = threadIdx.x, w = tid >> 6, lane = tid & 63;
    const int l15 = lane & 15, lr4 = lane >> 4;
    const int lg = (blockIdx.x & 7) * 96 + (blockIdx.x >> 3);   // XCD swizzle
    const int bh = lg / 24, bx = lg - bh * 24;
    const int q0 = bx * 64;
    const int qw = q0 + w * 16;
    const int myq = qw + l15;           // lane's q row
    const int myrow = w * 16 + l15;     // LDS row
    const size_t kv  = (size_t)bh * S_ * HD_;
    const size_t vtb = (size_t)bh * 64 * SP_;
    const int swz = (l15 & 7) << 1;

    // init wsm rows (wave-local) to -1e30
    {
        short ini = f2b(-1e30f);
        bf16x8 iv;
#pragma unroll
        for (int i = 0; i < 8; ++i) iv[i] = ini;
        short* base = wsm + w * 16 * 160;
#pragma unroll
        for (int i = 0; i < 5; ++i)
            *(bf16x8*)(base + (size_t)(i * 64 + lane) * 8) = iv;
    }
    // stage Q -> Kc rows 0..63 (pre-swizzled source, linear dest)
#pragma unroll
    for (int cc = 0; cc < 2; ++cc) {
        int slot = (w * 2 + cc) * 64 + lane;
        int r = slot >> 3, cb = slot & 7;
        int sq = q0 + r; sq = sq < S_ ? sq : S_ - 1;
        gload16(Qb + kv + (size_t)sq * 64 + ((cb ^ (r & 7)) * 8),
                Kc + (size_t)(w * 2 + cc) * 512);
    }
    __syncthreads();

    bf16x8 qA[2];
    {
        int r = myrow;
        qA[0] = *(const bf16x8*)(Kc + r * 64 + ((lr4 ^ (r & 7)) * 8));
        qA[1] = *(const bf16x8*)(Kc + r * 64 + (((4 + lr4) ^ (r & 7)) * 8));
    }

    // qpe: D[j][q] = pe_k . Q (log2 domain via Wq scale); full 9-tile write
    f32x4 zf = {0.f,0.f,0.f,0.f};
#pragma unroll
    for (int jt = 0; jt < 9; ++jt) {
        f32x4 a = zf;
#pragma unroll
        for (int kh = 0; kh < 2; ++kh) {
            bf16x8 pf = *(const bf16x8*)(pe_kb + (size_t)(jt * 16 + l15) * 64 + kh * 32 + lr4 * 8);
            a = __builtin_amdgcn_mfma_f32_16x16x32_bf16(pf, qA[kh], a, 0, 0, 0);
        }
        bf16x4 pk;
#pragma unroll
        for (int rr = 0; rr < 4; ++rr) pk[rr] = f2b(a[rr]);
        *(bf16x4*)(qpe + (size_t)myrow * 144 + jt * 16 + lr4 * 4) = pk;
    }
    const float qpe0   = b2f(qpe[myrow * 144 + 0]);
    const float qpe128 = b2f(qpe[myrow * 144 + 128]);
    __syncthreads();   // all waves done reading Kc (Q)

    float m = -1e30f, s0s = 0.f, s1s = 0.f;
    f32x4 o[4];
#pragma unroll
    for (int t = 0; t < 4; ++t) o[t] = zf;

    for (int c = 0; c < 12; ++c) {
        const int kc = c * 128;
        // stage K (128x64) + V^T (64x128), single buffer, 8 gload16/wave
#pragma unroll
        for (int cc = 0; cc < 4; ++cc) {
            int slot = (w * 4 + cc) * 64 + lane;
            int rK = slot >> 3, cbK = slot & 7;
            int sk = kc + rK; sk = sk < S_ ? sk : S_ - 1;
            gload16(Kb + kv + (size_t)sk * 64 + ((cbK ^ (rK & 7)) * 8),
                    Kc + (size_t)(w * 4 + cc) * 512);
            int rV = slot >> 4, cbV = slot & 15;
            gload16(Vtg + vtb + (size_t)rV * SP_ + kc + ((cbV ^ (rV & 7)) * 8),
                    Vt + (size_t)(w * 4 + cc) * 512);
        }
        __syncthreads();   // staging complete (syncthreads drains vmcnt)

#pragma unroll
        for (int half = 0; half < 2; ++half) {
            const int kb0 = kc + half * 64;

            // swapped QK^T over this half's 64 K rows
            __builtin_amdgcn_s_setprio(1);
            f32x4 sa[4];
#pragma unroll
            for (int t = 0; t < 4; ++t) {
                sa[t] = zf;
#pragma unroll
                for (int kh = 0; kh < 2; ++kh) {
                    int r = half * 64 + t * 16 + l15;
                    bf16x8 kB = *(const bf16x8*)(Kc + r * 64 + (((kh*4+lr4) ^ (r & 7)) * 8));
                    sa[t] = __builtin_amdgcn_mfma_f32_16x16x32_bf16(kB, qA[kh], sa[t], 0, 0, 0);
                }
            }
            __builtin_amdgcn_s_setprio(0);

            const bool all_lo = (kb0 + 63 - qw) <= -64;
            const bool all_hi = (kb0 - (qw + 15)) >= 64;
            const bool mixed  = !(all_lo || all_hi);
            const float ubias = all_lo ? qpe0 : qpe128;

            float lg2[4][4];
            float rm = -1e30f;
#pragma unroll
            for (int t = 0; t < 4; ++t)
#pragma unroll
                for (int rr = 0; rr < 4; ++rr) {
                    int k = kb0 + t * 16 + lr4 * 4 + rr;
                    int rel = k - myq;
                    float v;
                    if (mixed) {
                        int jc = rel < -64 ? 0 : (rel > 64 ? 128 : rel + 64);
                        v = sa[t][rr] + b2f(qpe[myrow * 144 + jc]);
                    } else {
                        v = sa[t][rr] + ubias;
                    }
                    if (k >= S_) v = -1e30f;
                    lg2[t][rr] = v;
                    rm = fmaxf(rm, v);
                    if (mixed && rel > -64 && rel < 64)
                        wsm[myrow * 160 + rel + 64] = f2b(v);
                }
            rm = fmaxf(rm, __shfl_xor(rm, 16));
            rm = fmaxf(rm, __shfl_xor(rm, 32));

            // defer-max: only rescale when growth exceeds 8 (log2 domain)
            if (!__all(rm <= m + 8.f)) {
                float nm = fmaxf(m, rm);
                float fac = exp2f(m - nm);
                m = nm; s0s *= fac; s1s *= fac;
                float fo[4];
#pragma unroll
                for (int rr = 0; rr < 4; ++rr) fo[rr] = __shfl(fac, lr4 * 4 + rr);
#pragma unroll
                for (int t = 0; t < 4; ++t)
#pragma unroll
                    for (int rr = 0; rr < 4; ++rr) o[t][rr] *= fo[rr];
            }

            // p = exp2, bucket partials, vectorized P writes into Pw[w]
            float ls0 = 0.f, ls1 = 0.f;
#pragma unroll
            for (int t = 0; t < 4; ++t) {
                bf16x4 pk;
#pragma unroll
                for (int rr = 0; rr < 4; ++rr) {
                    float p2 = exp2f(lg2[t][rr] - m);
                    pk[rr] = f2b(p2);
                    if (mixed) {
                        int rel = (kb0 + t * 16 + lr4 * 4 + rr) - myq;
                        if (rel <= -64) ls0 += p2; else if (rel >= 64) ls1 += p2;
                    } else if (all_lo) ls0 += p2; else ls1 += p2;
                }
                *(bf16x4*)(Pw[w] + l15 * 64 + (((t * 4 + lr4) ^ swz) << 2)) = pk;
            }
            ls0 += __shfl_xor(ls0, 16); ls0 += __shfl_xor(ls0, 32);
            ls1 += __shfl_xor(ls1, 16); ls1 += __shfl_xor(ls1, 32);
            s0s += ls0; s1s += ls1;

            // PV (P from wave-private Pw[w], V cols of this half)
            __builtin_amdgcn_s_setprio(1);
#pragma unroll
            for (int win = 0; win < 2; ++win) {
                bf16x8 pA = *(const bf16x8*)(Pw[w] + l15 * 64 + (((win * 8 + lr4 * 2) ^ swz) << 2));
#pragma unroll
                for (int td = 0; td < 4; ++td) {
                    int r = td * 16 + l15;
                    int cbv = half * 8 + win * 4 + lr4;
                    bf16x8 vB = *(const bf16x8*)(Vt + r * 128 + ((cbv ^ (r & 7)) * 8));
                    o[td] = __builtin_amdgcn_mfma_f32_16x16x32_bf16(pA, vB, o[td], 0, 0, 0);
                }
            }
            __builtin_amdgcn_s_setprio(0);
        }

        __syncthreads();   // all reads of Kc/Vt done; next iter may restage
    }

    // ---- epilogue (r7-exact, wave-local wsm traffic) ----
    short* rowp = wsm + (size_t)myrow * 160;
    float midsum = 0.f;
#pragma unroll
    for (int cc = 0; cc < 5; ++cc) {
        int off = (cc * 4 + lr4) * 8;
        bf16x8 mv = *(const bf16x8*)(rowp + off);
        bf16x8 ev;
#pragma unroll
        for (int jj = 0; jj < 8; ++jj) {
            float e = exp2f(b2f(mv[jj]) - m);
            ev[jj] = f2b(e);
            midsum += e;
        }
        *(bf16x8*)(rowp + off) = ev;
    }
    midsum += __shfl_xor(midsum, 16); midsum += __shfl_xor(midsum, 32);
    const float linv = 1.f / (s0s + s1s + midsum);
    if (lr4 == 0) { rowp[0] = f2b(s0s); rowp[128] = f2b(s1s); }

    // o += wsm-row . pe_v^T  (K = 160)
#pragma unroll
    for (int jh = 0; jh < 5; ++jh) {
        bf16x8 aW = *(const bf16x8*)(wsm + (size_t)myrow * 160 + jh * 32 + lr4 * 8);
#pragma unroll
        for (int td = 0; td < 4; ++td) {
            bf16x8 bW = *(const bf16x8*)(pe_vt + (size_t)(td * 16 + l15) * 160 + jh * 32 + lr4 * 8);
            o[td] = __builtin_amdgcn_mfma_f32_16x16x32_bf16(aW, bW, o[td], 0, 0, 0);
        }
    }

    // normalize (o rows = lr4*4+rr; inv lives on lane lr4*4+rr)
    {
        float fo[4];
#pragma unroll
        for (int rr = 0; rr < 4; ++rr) fo[rr] = __shfl(linv, lr4 * 4 + rr);
#pragma unroll
        for (int td = 0; td < 4; ++td)
#pragma unroll
            for (int rr = 0; rr < 4; ++rr) o[td][rr] *= fo[rr];
    }

    // stage hi -> Pw[w], lo -> wsm rows (both wave-local), then b128 stores
#pragma unroll
    for (int td = 0; td < 4; ++td)
#pragma unroll
        for (int rr = 0; rr < 4; ++rr) {
            int qrow = lr4 * 4 + rr;
            int d = td * 16 + l15;
            int inner = (((d >> 2) ^ ((qrow & 7) << 1)) << 2) + (d & 3);
            float v = o[td][rr];
            short hi = f2b(v);
            Pw[w][qrow * 64 + inner] = hi;
            wsm[(w * 16 + qrow) * 160 + inner] = f2b(v - b2f(hi));
        }
    {
        int b = bh >> 4, h = bh & 15;
        int qrow = lane >> 2;
        int q = q0 + w * 16 + qrow;
#pragma unroll
        for (int i = 0; i < 2; ++i) {
            int cb = (lane & 3) * 2 + i;
            int qws = (cb * 2) ^ ((qrow & 7) << 1);
            bf16x8 hv = *(const bf16x8*)(Pw[w] + qrow * 64 + qws * 4);
            bf16x8 lv = *(const bf16x8*)(wsm + (w * 16 + qrow) * 160 + qws * 4);
            if (q < S_) {
                size_t oo = ((size_t)(b * S_ + q)) * 1024 + h * 64 + cb * 8;
                *(bf16x8*)(hid_hi + oo) = hv;
                *(bf16x8*)(hid_lo + oo) = lv;
            }
        }
    }
}

// ---------------------------------------------------------------------------
extern "C" void kernel_launch(void* const* d_in, const int* in_sizes, int n_in,
                              void* d_out, int out_size, void* d_ws, size_t ws_size,
                              hipStream_t stream)
{
    const float* query = (const float*)d_in[0];
    const float* key   = (const float*)d_in[1];
    const float* value = (const float*)d_in[2];
    const float* Wq    = (const float*)d_in[3];
    const float* bq    = (const float*)d_in[4];
    const float* Wk    = (const float*)d_in[5];
    const float* bk    = (const float*)d_in[6];
    const float* Wv    = (const float*)d_in[7];
    const float* bv    = (const float*)d_in[8];
    const float* pe_k  = (const float*)d_in[9];
    const float* pe_v  = (const float*)d_in[10];
    const float* W_fc  = (const float*)d_in[11];
    const float* b_fc  = (const float*)d_in[12];

    char* W = (char*)d_ws;
    short* qb   = (short*)(W + 0);          // later: hid_hi
    short* kb   = (short*)(W + 6291456);    // later: hid_lo
    short* vb   = (short*)(W + 12582912);   // later: Vtg (transposed V)
    short* Vtg  = vb;
    short* Wqt  = (short*)(W + 18874368);
    short* Wkt  = (short*)(W + 20971520);
    short* Wvt  = (short*)(W + 23068672);
    short* Wfh  = (short*)(W + 25165824);
    short* Wfl  = (short*)(W + 27262976);
    short* Qp   = (short*)(W + 29360128);
    short* Kp   = (short*)(W + 35651584);
    short* Vp   = (short*)(W + 41943040);
    short* pekb = (short*)(W + 48234496);
    short* pevt = (short*)(W + 48252928);
    short* hidh = qb;
    short* hidl = kb;

    cvt_act3<<<dim3(1500, 3), 256, 0, stream>>>(query, key, value, qb, kb, vb);
    prep_w<<<1025, 256, 0, stream>>>(Wq, Wk, Wv, W_fc, pe_k, pe_v,
                                     Wqt, Wkt, Wvt, Wfh, Wfl, pekb, pevt);
    gemm_qkv<<<dim3(24, 8, 3), 256, 0, stream>>>(qb, kb, vb, Wqt, Wkt, Wvt,
                                                 bq, bk, bv, Qp, Kp, Vp);
    vtrans<<<dim3(24, 32), 256, 0, stream>>>(Vp, Vtg);
    attn_mfma<<<768, 256, 0, stream>>>(Qp, Kp, Vtg, pekb, pevt, hidh, hidl);
    gemm_fc<<<dim3(24, 8), 256, 0, stream>>>(hidh, hidl, Wfh, Wfl, b_fc, (float*)d_out);
}

// Round 9
// 260.613 us; speedup vs baseline: 1.1098x; 1.0716x over previous
//
#include <hip/hip_runtime.h>
#include <math.h>

#define B_     2
#define S_     1500
#define HID_   1024
#define NH_    16
#define HD_    64
#define M_     (B_*S_)   // 3000
#define SP_    1536      // padded S for transposed-V rows
#define LOG2E  1.4426950408889634f

typedef short bf16x8 __attribute__((ext_vector_type(8)));
typedef short bf16x4 __attribute__((ext_vector_type(4)));
typedef float f32x4  __attribute__((ext_vector_type(4)));

__device__ __forceinline__ float b2f(short s) {
    unsigned u = ((unsigned)(unsigned short)s) << 16;
    return __uint_as_float(u);
}
__device__ __forceinline__ short f2b(float f) {   // RNE, finite inputs
    unsigned u = __float_as_uint(f);
    unsigned r = (u + 0x7FFFu + ((u >> 16) & 1u)) >> 16;
    return (short)r;
}
__device__ __forceinline__ void gload16(const short* src, short* lds) {
    __builtin_amdgcn_global_load_lds(
        (const __attribute__((address_space(1))) void*)src,
        (__attribute__((address_space(3))) void*)lds, 16, 0, 0);
}

// ---------------------------------------------------------------------------
// f32 -> bf16 for the three activations, one launch
__global__ __launch_bounds__(256) void cvt_act3(
    const float* __restrict__ q, const float* __restrict__ k,
    const float* __restrict__ v, short* __restrict__ oq,
    short* __restrict__ ok, short* __restrict__ ov)
{
    const float* src = blockIdx.y == 0 ? q : blockIdx.y == 1 ? k : v;
    short* dst       = blockIdx.y == 0 ? oq : blockIdx.y == 1 ? ok : ov;
    int i = blockIdx.x * 256 + threadIdx.x;      // < 384000
    const float4* p = (const float4*)(src + (size_t)i * 8);
    float4 a = p[0], b = p[1];
    bf16x8 o;
    o[0]=f2b(a.x); o[1]=f2b(a.y); o[2]=f2b(a.z); o[3]=f2b(a.w);
    o[4]=f2b(b.x); o[5]=f2b(b.y); o[6]=f2b(b.z); o[7]=f2b(b.w);
    *(bf16x8*)(dst + (size_t)i * 8) = o;
}

// ---------------------------------------------------------------------------
// all weight prep in one launch; Wq/bq fold 0.125*log2e
__global__ __launch_bounds__(256) void prep_w(
    const float* __restrict__ Wq, const float* __restrict__ Wk,
    const float* __restrict__ Wv, const float* __restrict__ Wfc,
    const float* __restrict__ pe_k, const float* __restrict__ pe_v,
    short* __restrict__ Wqt, short* __restrict__ Wkt, short* __restrict__ Wvt,
    short* __restrict__ Wfh, short* __restrict__ Wfl,
    short* __restrict__ pe_kb, short* __restrict__ pe_vt)
{
    int z = blockIdx.x, tid = threadIdx.x;
    if (z == 1024) {
        for (int s = tid; s < 144 * 64; s += 256) {
            int j = s >> 6, d = s & 63;
            pe_kb[s] = (j < 129) ? f2b(pe_k[j * 64 + d]) : (short)0;
        }
        for (int s = tid; s < 64 * 160; s += 256) {
            int d = s / 160, j = s - d * 160;
            pe_vt[s] = (j < 129) ? f2b(pe_v[j * 64 + d]) : (short)0;
        }
        return;
    }
    __shared__ float T[64][65];
    const float* src; short* dhi; short* dlo = nullptr;
    int C, c0, r0; float scale = 1.f;
    if (z < 768) {
        int widx = z >> 8, rem = z & 255;
        int h = rem >> 4, rt = rem & 15;
        src = (widx == 0 ? Wq : widx == 1 ? Wk : Wv) + (size_t)h * 1024 * 64;
        dhi = (widx == 0 ? Wqt : widx == 1 ? Wkt : Wvt) + (size_t)h * 64 * 1024;
        scale = (widx == 0) ? 0.125f * LOG2E : 1.0f;
        C = 64; c0 = 0; r0 = rt * 64;
    } else {
        int idx = z - 768;
        src = Wfc; dhi = Wfh; dlo = Wfl;
        C = 1024; c0 = (idx >> 4) * 64; r0 = (idx & 15) * 64;
    }
#pragma unroll
    for (int i = 0; i < 4; ++i) {
        int slot = tid + i * 256;
        int r = slot >> 4, cg = (slot & 15) * 4;
        float4 v = *(const float4*)(src + (size_t)(r0 + r) * C + c0 + cg);
        T[r][cg+0] = v.x*scale; T[r][cg+1] = v.y*scale;
        T[r][cg+2] = v.z*scale; T[r][cg+3] = v.w*scale;
    }
    __syncthreads();
#pragma unroll
    for (int i = 0; i < 16; ++i) {
        int slot = tid + i * 256;
        int c = slot >> 6, r = slot & 63;
        float v = T[r][c];
        short hi = f2b(v);
        size_t o = (size_t)(c0 + c) * 1024 + r0 + r;
        dhi[o] = hi;
        if (dlo) dlo[o] = f2b(v - b2f(hi));
    }
}

// ---------------------------------------------------------------------------
// shared GEMM core: 128x128 tile, BK=64, global_load_lds staging (r4-proven)
__device__ __forceinline__ void gemm_core(
    const short* __restrict__ Ahi, const short* __restrict__ Alo,
    const short* __restrict__ Bhi, const short* __restrict__ Blo,
    int kIters, int m0, int n0, short* As, short* Bs, f32x4 (&acc)[4][4])
{
    const int tid = threadIdx.x, w = tid >> 6, lane = tid & 63;
    const int l15 = lane & 15, lr4 = lane >> 4;
    const int wr = w >> 1, wc = w & 1;

    for (int it = 0; it < kIters; ++it) {
        int kt = it * 64;
        int seg = kt >> 10, kk0 = kt & 1023;
        const short* Aseg = (seg == 1) ? Alo : Ahi;
        const short* Bseg = (seg == 2) ? Blo : Bhi;
        __syncthreads();
#pragma unroll
        for (int c = 0; c < 4; ++c) {
            int slot = (w * 4 + c) * 64 + lane;
            int r = slot >> 3, cb = slot & 7;
            int sm = m0 + r; sm = sm < M_ ? sm : M_ - 1;
            gload16(Aseg + (size_t)sm * 1024 + kk0 + ((cb ^ (r & 7)) * 8),
                    As + (size_t)(w * 4 + c) * 512);
            gload16(Bseg + (size_t)(n0 + r) * 1024 + kk0 + ((cb ^ (r & 7)) * 8),
                    Bs + (size_t)(w * 4 + c) * 512);
        }
        __syncthreads();
#pragma unroll
        for (int kh = 0; kh < 2; ++kh) {
            bf16x8 aF[4], bF[4];
#pragma unroll
            for (int mi = 0; mi < 4; ++mi) {
                int r = wr * 64 + mi * 16 + l15;
                aF[mi] = *(const bf16x8*)(As + r * 64 + (((kh*4+lr4) ^ (r & 7)) * 8));
            }
#pragma unroll
            for (int ni = 0; ni < 4; ++ni) {
                int r = wc * 64 + ni * 16 + l15;
                bF[ni] = *(const bf16x8*)(Bs + r * 64 + (((kh*4+lr4) ^ (r & 7)) * 8));
            }
#pragma unroll
            for (int mi = 0; mi < 4; ++mi)
#pragma unroll
                for (int ni = 0; ni < 4; ++ni)
                    acc[mi][ni] = __builtin_amdgcn_mfma_f32_16x16x32_bf16(
                        aF[mi], bF[ni], acc[mi][ni], 0, 0, 0);
        }
    }
}

// QKV projections, one launch (grid.z selects)
__global__ __launch_bounds__(256) void gemm_qkv(
    const short* __restrict__ qb, const short* __restrict__ kb,
    const short* __restrict__ vb, const short* __restrict__ Wqt,
    const short* __restrict__ Wkt, const short* __restrict__ Wvt,
    const float* __restrict__ bq, const float* __restrict__ bk,
    const float* __restrict__ bv,
    short* __restrict__ Qp, short* __restrict__ Kp, short* __restrict__ Vp)
{
    __shared__ short As[128 * 64];
    __shared__ short Bs[128 * 64];
    const int z = blockIdx.z;
    const short* A  = z == 0 ? qb : z == 1 ? kb : vb;
    const short* Bw = z == 0 ? Wqt : z == 1 ? Wkt : Wvt;
    const float* bias = z == 0 ? bq : z == 1 ? bk : bv;
    const float bscale = z == 0 ? 0.125f * LOG2E : 1.0f;
    short* out = z == 0 ? Qp : z == 1 ? Kp : Vp;
    const int m0 = blockIdx.x * 128, n0 = blockIdx.y * 128;

    f32x4 zf = {0.f,0.f,0.f,0.f};
    f32x4 acc[4][4];
#pragma unroll
    for (int i = 0; i < 4; ++i)
#pragma unroll
        for (int j = 0; j < 4; ++j) acc[i][j] = zf;

    gemm_core(A, A, Bw, Bw, 16, m0, n0, As, Bs, acc);

    const int tid = threadIdx.x, w = tid >> 6, lane = tid & 63;
    const int l15 = lane & 15, lr4 = lane >> 4;
    const int wr = w >> 1, wc = w & 1;
#pragma unroll
    for (int mi = 0; mi < 4; ++mi)
#pragma unroll
        for (int rr = 0; rr < 4; ++rr) {
            int m = m0 + wr * 64 + mi * 16 + lr4 * 4 + rr;
            if (m >= M_) continue;
            int b = m / S_, s = m - b * S_;
#pragma unroll
            for (int ni = 0; ni < 4; ++ni) {
                int n = n0 + wc * 64 + ni * 16 + l15;
                float v = acc[mi][ni][rr] + bias[n] * bscale;
                int h = n >> 6, d = n & 63;
                out[(((size_t)(b * NH_ + h)) * S_ + s) * HD_ + d] = f2b(v);
            }
        }
}

// final projection, 2-segment split-bf16 (Ahi*Bhi + Alo*Bhi), f32 out
__global__ __launch_bounds__(256) void gemm_fc(
    const short* __restrict__ Ahi, const short* __restrict__ Alo,
    const short* __restrict__ Bhi, const short* __restrict__ Blo,
    const float* __restrict__ bias, float* __restrict__ out)
{
    __shared__ short As[128 * 64];
    __shared__ short Bs[128 * 64];
    const int m0 = blockIdx.x * 128, n0 = blockIdx.y * 128;
    f32x4 zf = {0.f,0.f,0.f,0.f};
    f32x4 acc[4][4];
#pragma unroll
    for (int i = 0; i < 4; ++i)
#pragma unroll
        for (int j = 0; j < 4; ++j) acc[i][j] = zf;

    gemm_core(Ahi, Alo, Bhi, Blo, 32, m0, n0, As, Bs, acc);

    const int tid = threadIdx.x, w = tid >> 6, lane = tid & 63;
    const int l15 = lane & 15, lr4 = lane >> 4;
    const int wr = w >> 1, wc = w & 1;
#pragma unroll
    for (int mi = 0; mi < 4; ++mi)
#pragma unroll
        for (int rr = 0; rr < 4; ++rr) {
            int m = m0 + wr * 64 + mi * 16 + lr4 * 4 + rr;
            if (m >= M_) continue;
#pragma unroll
            for (int ni = 0; ni < 4; ++ni) {
                int n = n0 + wc * 64 + ni * 16 + l15;
                out[(size_t)m * 1024 + n] = acc[mi][ni][rr] + bias[n];
            }
        }
}

// ---------------------------------------------------------------------------
// V panel transpose: [bh][s][d] -> [bh][d][SP_], with the PV K-permutation
// baked into the column order (per 32-col window): col c holds original
// k(c) = 32*(c>>5) + 16*((c>>2)&1) + 4*((c>>3)&3) + (c&3).
__global__ __launch_bounds__(256) void vtrans(
    const short* __restrict__ Vp, short* __restrict__ Vtg)
{
    __shared__ short T[64][72];
    const int bh = blockIdx.y, s0 = blockIdx.x * 64, tid = threadIdx.x;
    const size_t kv = (size_t)bh * S_ * 64;
#pragma unroll
    for (int i = 0; i < 2; ++i) {
        int slot = tid + i * 256;
        int r = slot >> 3, cb = slot & 7;
        int ss = s0 + r; ss = ss < S_ ? ss : S_ - 1;
        bf16x8 v = *(const bf16x8*)(Vp + kv + (size_t)ss * 64 + cb * 8);
        *(bf16x8*)(&T[r][cb * 8]) = v;
    }
    __syncthreads();
#pragma unroll
    for (int i = 0; i < 2; ++i) {
        int slot = tid + i * 256;
        int d = slot >> 3, cg = slot & 7;
        bf16x8 v;
#pragma unroll
        for (int j = 0; j < 8; ++j) {
            int kk = 32 * (cg >> 2) + ((j >> 2) & 1) * 16 + (cg & 3) * 4 + (j & 3);
            v[j] = T[kk][d];
        }
        *(bf16x8*)(Vtg + ((size_t)bh * 64 + d) * SP_ + s0 + cg * 8) = v;
    }
}

// ---------------------------------------------------------------------------
// Fused flash attention: KVBLK=128, merged single softmax pass per chunk,
// zero-LDS P (register A-fragments + permuted V^T), exp2 domain, defer-max.
// LDS = 70 KB (no Pw buffer) -> 2 blocks/CU.
__global__ __launch_bounds__(256) void attn_mfma(
    const short* __restrict__ Qb, const short* __restrict__ Kb,
    const short* __restrict__ Vtg, const short* __restrict__ pe_kb,
    const short* __restrict__ pe_vt,
    short* __restrict__ hid_hi, short* __restrict__ hid_lo)
{
    __shared__ short Kc[128 * 64];    // K chunk [k=128][d=64] (Q in prologue)
    __shared__ short Vt[64 * 128];    // V^T chunk [d=64][k=128, permuted]
    __shared__ short qpe[64 * 144];   // [row][j] Shaw key-bias (log2 domain)
    __shared__ short wsm[64 * 160];   // [row][j] raw band logits -> e-values

    const int tid = threadIdx.x, w = tid >> 6, lane = tid & 63;
    const int l15 = lane & 15, lr4 = lane >> 4;
    const int lg = (blockIdx.x & 7) * 96 + (blockIdx.x >> 3);   // XCD swizzle
    const int bh = lg / 24, bx = lg - bh * 24;
    const int q0 = bx * 64;
    const int qw = q0 + w * 16;
    const int myq = qw + l15;           // lane's q row
    const int myrow = w * 16 + l15;     // LDS row
    const size_t kv  = (size_t)bh * S_ * HD_;
    const size_t vtb = (size_t)bh * 64 * SP_;

    // init wsm rows (wave-local) to -1e30
    {
        short ini = f2b(-1e30f);
        bf16x8 iv;
#pragma unroll
        for (int i = 0; i < 8; ++i) iv[i] = ini;
        short* base = wsm + w * 16 * 160;
#pragma unroll
        for (int i = 0; i < 5; ++i)
            *(bf16x8*)(base + (size_t)(i * 64 + lane) * 8) = iv;
    }
    // stage Q -> Kc rows 0..63 (pre-swizzled source, linear dest)
#pragma unroll
    for (int cc = 0; cc < 2; ++cc) {
        int slot = (w * 2 + cc) * 64 + lane;
        int r = slot >> 3, cb = slot & 7;
        int sq = q0 + r; sq = sq < S_ ? sq : S_ - 1;
        gload16(Qb + kv + (size_t)sq * 64 + ((cb ^ (r & 7)) * 8),
                Kc + (size_t)(w * 2 + cc) * 512);
    }
    __syncthreads();

    bf16x8 qA[2];
    {
        int r = myrow;
        qA[0] = *(const bf16x8*)(Kc + r * 64 + ((lr4 ^ (r & 7)) * 8));
        qA[1] = *(const bf16x8*)(Kc + r * 64 + (((4 + lr4) ^ (r & 7)) * 8));
    }

    // qpe: D[j][q] = pe_k . Q (log2 domain via Wq scale); full 9-tile write
    f32x4 zf = {0.f,0.f,0.f,0.f};
#pragma unroll
    for (int jt = 0; jt < 9; ++jt) {
        f32x4 a = zf;
#pragma unroll
        for (int kh = 0; kh < 2; ++kh) {
            bf16x8 pf = *(const bf16x8*)(pe_kb + (size_t)(jt * 16 + l15) * 64 + kh * 32 + lr4 * 8);
            a = __builtin_amdgcn_mfma_f32_16x16x32_bf16(pf, qA[kh], a, 0, 0, 0);
        }
        bf16x4 pk;
#pragma unroll
        for (int rr = 0; rr < 4; ++rr) pk[rr] = f2b(a[rr]);
        *(bf16x4*)(qpe + (size_t)myrow * 144 + jt * 16 + lr4 * 4) = pk;
    }
    const float qpe0   = b2f(qpe[myrow * 144 + 0]);
    const float qpe128 = b2f(qpe[myrow * 144 + 128]);
    __syncthreads();   // all waves done reading Kc (Q)

    float m = -1e30f, s0s = 0.f, s1s = 0.f;
    f32x4 o[4];
#pragma unroll
    for (int t = 0; t < 4; ++t) o[t] = zf;

    for (int c = 0; c < 12; ++c) {
        const int kc = c * 128;
        // stage K (128x64) + V^T (64x128), single buffer, 8 gload16/wave
#pragma unroll
        for (int cc = 0; cc < 4; ++cc) {
            int slot = (w * 4 + cc) * 64 + lane;
            int rK = slot >> 3, cbK = slot & 7;
            int sk = kc + rK; sk = sk < S_ ? sk : S_ - 1;
            gload16(Kb + kv + (size_t)sk * 64 + ((cbK ^ (rK & 7)) * 8),
                    Kc + (size_t)(w * 4 + cc) * 512);
            int rV = slot >> 4, cbV = slot & 15;
            gload16(Vtg + vtb + (size_t)rV * SP_ + kc + ((cbV ^ (rV & 7)) * 8),
                    Vt + (size_t)(w * 4 + cc) * 512);
        }
        __syncthreads();   // staging complete (syncthreads drains vmcnt)

        // swapped QK^T over all 8 k-tiles (both halves)
        __builtin_amdgcn_s_setprio(1);
        f32x4 sa[8];
#pragma unroll
        for (int t8 = 0; t8 < 8; ++t8) {
            sa[t8] = zf;
#pragma unroll
            for (int kh = 0; kh < 2; ++kh) {
                int r = t8 * 16 + l15;
                bf16x8 kB = *(const bf16x8*)(Kc + r * 64 + (((kh*4+lr4) ^ (r & 7)) * 8));
                sa[t8] = __builtin_amdgcn_mfma_f32_16x16x32_bf16(kB, qA[kh], sa[t8], 0, 0, 0);
            }
        }
        __builtin_amdgcn_s_setprio(0);

        // per-half bias classification
        const bool lo0 = (kc +  63 - qw) <= -64, hi0 = (kc       - (qw + 15)) >= 64;
        const bool lo1 = (kc + 127 - qw) <= -64, hi1 = (kc + 64  - (qw + 15)) >= 64;
        const bool mx0 = !(lo0 || hi0), mx1 = !(lo1 || hi1);
        const float ub0 = lo0 ? qpe0 : qpe128;
        const float ub1 = lo1 ? qpe0 : qpe128;

        // logits + single max pass over 32 values
        float lg2[8][4];
        float rm = -1e30f;
#pragma unroll
        for (int t8 = 0; t8 < 8; ++t8) {
            const bool mx = (t8 < 4) ? mx0 : mx1;
            const float ub = (t8 < 4) ? ub0 : ub1;
#pragma unroll
            for (int rr = 0; rr < 4; ++rr) {
                int k = kc + t8 * 16 + lr4 * 4 + rr;
                int rel = k - myq;
                float v;
                if (mx) {
                    int jc = rel < -64 ? 0 : (rel > 64 ? 128 : rel + 64);
                    v = sa[t8][rr] + b2f(qpe[myrow * 144 + jc]);
                } else {
                    v = sa[t8][rr] + ub;
                }
                if (k >= S_) v = -1e30f;
                lg2[t8][rr] = v;
                rm = fmaxf(rm, v);
                if (mx && rel > -64 && rel < 64)
                    wsm[myrow * 160 + rel + 64] = f2b(v);
            }
        }
        rm = fmaxf(rm, __shfl_xor(rm, 16));
        rm = fmaxf(rm, __shfl_xor(rm, 32));

        // defer-max: only rescale when growth exceeds 8 (log2 domain)
        if (!__all(rm <= m + 8.f)) {
            float nm = fmaxf(m, rm);
            float fac = exp2f(m - nm);
            m = nm; s0s *= fac; s1s *= fac;
            float fo[4];
#pragma unroll
            for (int rr = 0; rr < 4; ++rr) fo[rr] = __shfl(fac, lr4 * 4 + rr);
#pragma unroll
            for (int t = 0; t < 4; ++t)
#pragma unroll
                for (int rr = 0; rr < 4; ++rr) o[t][rr] *= fo[rr];
        }

        // p = exp2 -> REGISTER A-fragments (zero-LDS P), bucket partials
        bf16x8 pa[2][2];   // [half][win]; pa[h][wn][4*(tt&1)+rr] = P(t=h*4+2*wn+(tt&1), rr)
        float ls0 = 0.f, ls1 = 0.f;
#pragma unroll
        for (int t8 = 0; t8 < 8; ++t8) {
            const int h = t8 >> 2, tt = t8 & 3;
            const int wn = tt >> 1, sl = (tt & 1) * 4;
            const bool mx = h ? mx1 : mx0;
            const bool alo = h ? lo1 : lo0;
#pragma unroll
            for (int rr = 0; rr < 4; ++rr) {
                float p2 = exp2f(lg2[t8][rr] - m);
                pa[h][wn][sl + rr] = f2b(p2);
                if (mx) {
                    int rel = (kc + t8 * 16 + lr4 * 4 + rr) - myq;
                    if (rel <= -64) ls0 += p2; else if (rel >= 64) ls1 += p2;
                } else if (alo) ls0 += p2; else ls1 += p2;
            }
        }
        ls0 += __shfl_xor(ls0, 16); ls0 += __shfl_xor(ls0, 32);
        ls1 += __shfl_xor(ls1, 16); ls1 += __shfl_xor(ls1, 32);
        s0s += ls0; s1s += ls1;

        // PV both halves: A from registers, V columns permuted to match
        __builtin_amdgcn_s_setprio(1);
#pragma unroll
        for (int h = 0; h < 2; ++h)
#pragma unroll
            for (int wn = 0; wn < 2; ++wn)
#pragma unroll
                for (int td = 0; td < 4; ++td) {
                    int r = td * 16 + l15;
                    int cbv = h * 8 + wn * 4 + lr4;
                    bf16x8 vB = *(const bf16x8*)(Vt + r * 128 + ((cbv ^ (r & 7)) * 8));
                    o[td] = __builtin_amdgcn_mfma_f32_16x16x32_bf16(pa[h][wn], vB, o[td], 0, 0, 0);
                }
        __builtin_amdgcn_s_setprio(0);

        __syncthreads();   // all reads of Kc/Vt done; next iter may restage
    }

    // ---- epilogue (wave-local LDS traffic) ----
    short* rowp = wsm + (size_t)myrow * 160;
    float midsum = 0.f;
#pragma unroll
    for (int cc = 0; cc < 5; ++cc) {
        int off = (cc * 4 + lr4) * 8;
        bf16x8 mv = *(const bf16x8*)(rowp + off);
        bf16x8 ev;
#pragma unroll
        for (int jj = 0; jj < 8; ++jj) {
            float e = exp2f(b2f(mv[jj]) - m);
            ev[jj] = f2b(e);
            midsum += e;
        }
        *(bf16x8*)(rowp + off) = ev;
    }
    midsum += __shfl_xor(midsum, 16); midsum += __shfl_xor(midsum, 32);
    const float linv = 1.f / (s0s + s1s + midsum);
    if (lr4 == 0) { rowp[0] = f2b(s0s); rowp[128] = f2b(s1s); }

    // o += wsm-row . pe_v^T  (K = 160)
#pragma unroll
    for (int jh = 0; jh < 5; ++jh) {
        bf16x8 aW = *(const bf16x8*)(wsm + (size_t)myrow * 160 + jh * 32 + lr4 * 8);
#pragma unroll
        for (int td = 0; td < 4; ++td) {
            bf16x8 bW = *(const bf16x8*)(pe_vt + (size_t)(td * 16 + l15) * 160 + jh * 32 + lr4 * 8);
            o[td] = __builtin_amdgcn_mfma_f32_16x16x32_bf16(aW, bW, o[td], 0, 0, 0);
        }
    }

    // normalize (o rows = lr4*4+rr; inv lives on lane lr4*4+rr)
    {
        float fo[4];
#pragma unroll
        for (int rr = 0; rr < 4; ++rr) fo[rr] = __shfl(linv, lr4 * 4 + rr);
#pragma unroll
        for (int td = 0; td < 4; ++td)
#pragma unroll
            for (int rr = 0; rr < 4; ++rr) o[td][rr] *= fo[rr];
    }

    // stage hi -> wsm rows [0..63] (band consumed), lo -> qpe rows [0..63]
    // (qpe dead); wave-local; then coalesced b128 stores
#pragma unroll
    for (int td = 0; td < 4; ++td)
#pragma unroll
        for (int rr = 0; rr < 4; ++rr) {
            int qrow = lr4 * 4 + rr;
            int d = td * 16 + l15;
            int inner = (((d >> 2) ^ ((qrow & 7) << 1)) << 2) + (d & 3);
            float v = o[td][rr];
            short hi = f2b(v);
            wsm[(w * 16 + qrow) * 160 + inner] = hi;
            qpe[(w * 16 + qrow) * 144 + inner] = f2b(v - b2f(hi));
        }
    {
        int b = bh >> 4, h = bh & 15;
        int qrow = lane >> 2;
        int q = q0 + w * 16 + qrow;
#pragma unroll
        for (int i = 0; i < 2; ++i) {
            int cb = (lane & 3) * 2 + i;
            int qws = (cb * 2) ^ ((qrow & 7) << 1);
            bf16x8 hv = *(const bf16x8*)(wsm + (w * 16 + qrow) * 160 + qws * 4);
            bf16x8 lv = *(const bf16x8*)(qpe + (w * 16 + qrow) * 144 + qws * 4);
            if (q < S_) {
                size_t oo = ((size_t)(b * S_ + q)) * 1024 + h * 64 + cb * 8;
                *(bf16x8*)(hid_hi + oo) = hv;
                *(bf16x8*)(hid_lo + oo) = lv;
            }
        }
    }
}

// ---------------------------------------------------------------------------
extern "C" void kernel_launch(void* const* d_in, const int* in_sizes, int n_in,
                              void* d_out, int out_size, void* d_ws, size_t ws_size,
                              hipStream_t stream)
{
    const float* query = (const float*)d_in[0];
    const float* key   = (const float*)d_in[1];
    const float* value = (const float*)d_in[2];
    const float* Wq    = (const float*)d_in[3];
    const float* bq    = (const float*)d_in[4];
    const float* Wk    = (const float*)d_in[5];
    const float* bk    = (const float*)d_in[6];
    const float* Wv    = (const float*)d_in[7];
    const float* bv    = (const float*)d_in[8];
    const float* pe_k  = (const float*)d_in[9];
    const float* pe_v  = (const float*)d_in[10];
    const float* W_fc  = (const float*)d_in[11];
    const float* b_fc  = (const float*)d_in[12];

    char* W = (char*)d_ws;
    short* qb   = (short*)(W + 0);          // later: hid_hi
    short* kb   = (short*)(W + 6291456);    // later: hid_lo
    short* vb   = (short*)(W + 12582912);   // later: Vtg (transposed V)
    short* Vtg  = vb;
    short* Wqt  = (short*)(W + 18874368);
    short* Wkt  = (short*)(W + 20971520);
    short* Wvt  = (short*)(W + 23068672);
    short* Wfh  = (short*)(W + 25165824);
    short* Wfl  = (short*)(W + 27262976);
    short* Qp   = (short*)(W + 29360128);
    short* Kp   = (short*)(W + 35651584);
    short* Vp   = (short*)(W + 41943040);
    short* pekb = (short*)(W + 48234496);
    short* pevt = (short*)(W + 48252928);
    short* hidh = qb;
    short* hidl = kb;

    cvt_act3<<<dim3(1500, 3), 256, 0, stream>>>(query, key, value, qb, kb, vb);
    prep_w<<<1025, 256, 0, stream>>>(Wq, Wk, Wv, W_fc, pe_k, pe_v,
                                     Wqt, Wkt, Wvt, Wfh, Wfl, pekb, pevt);
    gemm_qkv<<<dim3(24, 8, 3), 256, 0, stream>>>(qb, kb, vb, Wqt, Wkt, Wvt,
                                                 bq, bk, bv, Qp, Kp, Vp);
    vtrans<<<dim3(24, 32), 256, 0, stream>>>(Vp, Vtg);
    attn_mfma<<<768, 256, 0, stream>>>(Qp, Kp, Vtg, pekb, pevt, hidh, hidl);
    gemm_fc<<<dim3(24, 8), 256, 0, stream>>>(hidh, hidl, Wfh, Wfl, b_fc, (float*)d_out);
}